// Round 1
// baseline (503.261 us; speedup 1.0000x reference)
//
#include <hip/hip_runtime.h>
#include <stdint.h>

// DeformationGraph: 65536 pts x 4096 nodes, top-20 by squared distance,
// weight-blended rigid transform gather.
//
// Design:
//  - 1 thread per point, grid 256x256 (1 block/CU, 1 wave/SIMD).
//  - Scan all 4096 nodes; key = (fp32 d2 bits >> 11) << 12 | node_idx packed
//    in one u32 (monotone in d2, stable low-idx tie-break like jax top_k).
//  - Candidates beating the (stale) 20th-best threshold are pushed to a
//    per-lane LDS stack (4 ops); stacks are merged into a 20-deep sorted
//    register list (umin/umax chain, 2 ops/level) at geometric chunk
//    boundaries 32,64,...,4096 -> divergence cost amortized.
//  - Exact d2 recomputed for the selected 20 with the reference formula
//    (sp + sv - 2*dot) for weights + far flag (razor-edge safety).
__device__ __forceinline__ uint32_t umin32(uint32_t a, uint32_t b) { return a < b ? a : b; }
__device__ __forceinline__ uint32_t umax32(uint32_t a, uint32_t b) { return a > b ? a : b; }

#define NPTS   65536
#define NNODES 4096
#define KSEL   20
#define CAP    60
#define BT     256

// Insert x into ascending sorted m[0..19], dropping old max. No-op if x >= m[19].
__device__ __forceinline__ void insert20(uint32_t m[KSEL], uint32_t x) {
#pragma unroll
  for (int k = KSEL - 1; k >= 1; --k)
    m[k] = umin32(m[k], umax32(m[k - 1], x));
  m[0] = umin32(m[0], x);
}

// Float threshold equal to the quantized-key floor of m19 (clamped to FLT_MAX
// so the 0xFFFFFFFF sentinel doesn't turn into a NaN).
__device__ __forceinline__ float thr_from(uint32_t m19) {
  return __uint_as_float(umin32((m19 >> 12) << 11, 0x7F7FFFFFu));
}

__global__ __launch_bounds__(BT) void dg_topk_blend(
    const float* __restrict__ inp, const float* __restrict__ vd,
    const float* __restrict__ Rm, const float* __restrict__ gv,
    const float* __restrict__ tv, float* __restrict__ out)
{
  __shared__ uint32_t st[CAP * BT];   // per-lane candidate stacks, 60 KB
  const int tid = threadIdx.x;
  const int gi  = blockIdx.x * BT + tid;

  const float p0 = inp[gi * 35 + 0];
  const float p1 = inp[gi * 35 + 1];
  const float p2 = inp[gi * 35 + 2];
  const float sp = p0 * p0 + p1 * p1 + p2 * p2;

  uint32_t m[KSEL];
#pragma unroll
  for (int k = 0; k < KSEL; ++k) m[k] = 0xFFFFFFFFu;
  int cnt = 0;
  float thr = __uint_as_float(0x7F7FFFFFu);  // FLT_MAX: first chunk pushes all

  int lo = 0;
#pragma unroll
  for (int c = 0; c < 8; ++c) {              // chunks end at 32,64,...,4096
    const int hi = 32 << c;
#pragma unroll 4
    for (int j = lo; j < hi; ++j) {          // j wave-uniform -> s_load of vd
      const float v0 = vd[j * 3 + 0];
      const float v1 = vd[j * 3 + 1];
      const float v2 = vd[j * 3 + 2];
      const float sv = v0 * v0 + v1 * v1 + v2 * v2;
      const float dt = p0 * v0 + p1 * v1 + p2 * v2;
      float d2 = (sp + sv) - 2.0f * dt;      // reference's formula
      d2 = fmaxf(d2, 0.0f);                  // keep uint key monotone
      if (d2 < thr) {
        const uint32_t packed =
            ((__float_as_uint(d2) & 0xFFFFF800u) << 1) | (uint32_t)j;
        st[cnt * BT + tid] = packed;
        ++cnt;
        if (cnt == CAP) {                    // essentially-never overflow drain
          for (int q = 0; q < cnt; ++q) {
            const uint32_t x = st[q * BT + tid];
            if (x < m[KSEL - 1]) insert20(m, x);
          }
          cnt = 0;
          thr = thr_from(m[KSEL - 1]);
        }
      }
    }
    // chunk-boundary merge: per-lane stacks, lanes run concurrently
    for (int q = 0; q < cnt; ++q) {
      const uint32_t x = st[q * BT + tid];
      if (x < m[KSEL - 1]) insert20(m, x);
    }
    cnt = 0;
    thr = thr_from(m[KSEL - 1]);
    lo = hi;
  }

  // ---- exact d2 recompute for the selected 20 (reference formula) ----
  int   id[KSEL];
  float d [KSEL];
  float dmin =  1e30f;
  float dmax = -1e30f;
#pragma unroll
  for (int k = 0; k < KSEL; ++k) {
    id[k] = (int)(m[k] & 0xFFFu);
    const float v0 = vd[id[k] * 3 + 0];
    const float v1 = vd[id[k] * 3 + 1];
    const float v2 = vd[id[k] * 3 + 2];
    const float sv = v0 * v0 + v1 * v1 + v2 * v2;
    const float dt = p0 * v0 + p1 * v1 + p2 * v2;
    d[k] = (sp + sv) - 2.0f * dt;            // raw (may be slightly negative)
    dmin = fminf(dmin, d[k]);
    dmax = fmaxf(dmax, d[k]);
  }

  // ---- weights + blend ----
  const float invmax = 1.0f / dmax;
  float wsum = 0.0f, pb0 = 0.0f, pb1 = 0.0f, pb2 = 0.0f;
  float rb[9];
#pragma unroll
  for (int a = 0; a < 9; ++a) rb[a] = 0.0f;

#pragma unroll
  for (int k = 0; k < KSEL; ++k) {
    const float u = 1.0f - d[k] * invmax;
    const float w = u * u;
    wsum += w;
    const float* Rp = Rm + id[k] * 9;
    const float r00 = Rp[0], r01 = Rp[1], r02 = Rp[2];
    const float r10 = Rp[3], r11 = Rp[4], r12 = Rp[5];
    const float r20 = Rp[6], r21 = Rp[7], r22 = Rp[8];
    const float g0 = gv[id[k] * 3 + 0];
    const float g1 = gv[id[k] * 3 + 1];
    const float g2 = gv[id[k] * 3 + 2];
    const float t0 = tv[id[k] * 3 + 0];
    const float t1 = tv[id[k] * 3 + 1];
    const float t2 = tv[id[k] * 3 + 2];
    const float x0 = p0 - g0 - t0;
    const float x1 = p1 - g1 - t1;
    const float x2 = p2 - g2 - t2;
    // p_i = sum_j R[j][i] * x_j + g_i   (einsum 'nkji,nkj->nki')
    const float q0 = r00 * x0 + r10 * x1 + r20 * x2 + g0;
    const float q1 = r01 * x0 + r11 * x1 + r21 * x2 + g1;
    const float q2 = r02 * x0 + r12 * x1 + r22 * x2 + g2;
    pb0 += w * q0;  pb1 += w * q1;  pb2 += w * q2;
    // R_blend[a][b] += w * R[b][a]  (R_inv = transpose)
    rb[0] += w * r00; rb[1] += w * r10; rb[2] += w * r20;
    rb[3] += w * r01; rb[4] += w * r11; rb[5] += w * r21;
    rb[6] += w * r02; rb[7] += w * r12; rb[8] += w * r22;
  }

  const float inw = 1.0f / wsum;
  pb0 *= inw; pb1 *= inw; pb2 *= inw;
  if (dmin > 0.00021f) pb0 = 1000000000.0f;  // far flag on col 0, post-blend

  float* po = out + (size_t)gi * 3;
  po[0] = pb0; po[1] = pb1; po[2] = pb2;
  float* ro = out + (size_t)NPTS * 3 + (size_t)gi * 9;
#pragma unroll
  for (int a = 0; a < 9; ++a) ro[a] = rb[a] * inw;
}

extern "C" void kernel_launch(void* const* d_in, const int* in_sizes, int n_in,
                              void* d_out, int out_size, void* d_ws, size_t ws_size,
                              hipStream_t stream) {
  const float* inp = (const float*)d_in[0];   // (65536, 35)
  const float* vd  = (const float*)d_in[1];   // (4096, 3)
  const float* Rm  = (const float*)d_in[2];   // (4096, 3, 3)
  const float* gv  = (const float*)d_in[3];   // (4096, 3)
  const float* tv  = (const float*)d_in[4];   // (4096, 3)
  float* out = (float*)d_out;                 // 65536*3 then 65536*9
  dg_topk_blend<<<NPTS / BT, BT, 0, stream>>>(inp, vd, Rm, gv, tv, out);
}

// Round 2
// 267.769 us; speedup vs baseline: 1.8795x; 1.8795x over previous
//
#include <hip/hip_runtime.h>
#include <stdint.h>

// DeformationGraph: 65536 pts x 4096 nodes, top-20 by squared distance,
// weight-blended rigid transform gather.
//
// R2 design:
//  - S=4 node-split per point: thread (p,q) scans nodes [q*1024,(q+1)*1024).
//    262144 threads -> 16 waves/CU (was 4) for latency hiding.
//  - Prep kernel packs nodes as float4(v0,v1,v2,|v|^2) in d_ws -> scan iter is
//    1 dwordx4 load + ~6 VALU.
//  - Per-thread top-20 via packed u32 keys (d2-bits<<12 | idx, monotone,
//    stable tie-break) with per-lane LDS candidate stacks + geometric chunk
//    merges (divergence amortized).
//  - 4 partial lists merged IN-WAVE: lanes q*16+p hold point p's quarters;
//    Batcher half-cleaner via shfl_xor (pad to 32 with UINT_MAX) + 5-stage
//    bitonic resort, 2 rounds -> all 4 lanes share the final top-20 set.
//  - Blend distributed: each lane handles 5 of the 20 neighbors with EXACT
//    reference-formula d2 recompute (far-flag razor edge), then 13-value
//    shfl_xor reduce; lane q==0 writes.

#define NPTS   65536
#define NNODES 4096
#define KSEL   20
#define CAP    36
#define BT     256
#define PPB    64      // points per block (256 threads / 4 quarters)

__device__ __forceinline__ uint32_t umin32(uint32_t a, uint32_t b) { return a < b ? a : b; }
__device__ __forceinline__ uint32_t umax32(uint32_t a, uint32_t b) { return a > b ? a : b; }
__device__ __forceinline__ void cmpswap(uint32_t& a, uint32_t& b) {
  const uint32_t lo = umin32(a, b), hi = umax32(a, b); a = lo; b = hi;
}

// Insert x into ascending sorted m[0..19], dropping old max. No-op if x >= m[19].
__device__ __forceinline__ void insert20(uint32_t m[KSEL], uint32_t x) {
#pragma unroll
  for (int k = KSEL - 1; k >= 1; --k)
    m[k] = umin32(m[k], umax32(m[k - 1], x));
  m[0] = umin32(m[0], x);
}

// Float threshold = quantized-key floor of m19 (clamped so sentinel != NaN).
__device__ __forceinline__ float thr_from(uint32_t m19) {
  return __uint_as_float(umin32((m19 >> 12) << 11, 0x7F7FFFFFu));
}

__global__ void pack_nodes(const float* __restrict__ vd, float4* __restrict__ nt) {
  const int j = blockIdx.x * 256 + threadIdx.x;
  const float v0 = vd[j * 3 + 0], v1 = vd[j * 3 + 1], v2 = vd[j * 3 + 2];
  nt[j] = make_float4(v0, v1, v2, v0 * v0 + v1 * v1 + v2 * v2);
}

template <bool TBL>
__global__ __launch_bounds__(BT, 4) void dg_kernel(
    const float* __restrict__ inp, const float* __restrict__ vd,
    const float* __restrict__ Rm, const float* __restrict__ gv,
    const float* __restrict__ tv, const float4* __restrict__ nt,
    float* __restrict__ out)
{
  __shared__ uint32_t st[CAP * BT];   // per-lane candidate stacks, 36 KB
  const int tid = threadIdx.x;
  const int q   = (tid >> 4) & 3;     // node-quarter within wave
  const int pl  = tid & 15;           // point-lane within wave
  const int wv  = tid >> 6;           // wave in block
  const int gi  = blockIdx.x * PPB + wv * 16 + pl;   // point index

  const float p0 = inp[gi * 35 + 0];
  const float p1 = inp[gi * 35 + 1];
  const float p2 = inp[gi * 35 + 2];
  const float sp = p0 * p0 + p1 * p1 + p2 * p2;

  uint32_t m[KSEL];
#pragma unroll
  for (int k = 0; k < KSEL; ++k) m[k] = 0xFFFFFFFFu;
  int cnt = 0;
  float thr = __uint_as_float(0x7F7FFFFFu);   // FLT_MAX: chunk 0 pushes all

  const int jbase = q * (NNODES / 4);
  int lo = 0;
#pragma unroll
  for (int c = 0; c < 6; ++c) {               // chunk ends: 32,64,...,1024
    const int hi = 32 << c;
#pragma unroll 4
    for (int i = lo; i < hi; ++i) {
      const int j = jbase + i;
      float v0, v1, v2, sv;
      if (TBL) {
        const float4 n = nt[j];
        v0 = n.x; v1 = n.y; v2 = n.z; sv = n.w;
      } else {
        v0 = vd[j * 3 + 0]; v1 = vd[j * 3 + 1]; v2 = vd[j * 3 + 2];
        sv = v0 * v0 + v1 * v1 + v2 * v2;
      }
      const float dt = p0 * v0 + p1 * v1 + p2 * v2;
      float d2 = (sp + sv) - 2.0f * dt;       // reference's formula
      d2 = fmaxf(d2, 0.0f);                   // keep uint key monotone
      if (d2 < thr) {
        st[cnt * BT + tid] =
            ((__float_as_uint(d2) & 0xFFFFF800u) << 1) | (uint32_t)j;
        if (++cnt == CAP) {                   // near-never overflow drain
          for (int u = 0; u < cnt; ++u) {
            const uint32_t x = st[u * BT + tid];
            if (x < m[KSEL - 1]) insert20(m, x);
          }
          cnt = 0;
          thr = thr_from(m[KSEL - 1]);
        }
      }
    }
    for (int u = 0; u < cnt; ++u) {           // chunk-boundary merge
      const uint32_t x = st[u * BT + tid];
      if (x < m[KSEL - 1]) insert20(m, x);
    }
    cnt = 0;
    thr = thr_from(m[KSEL - 1]);
    lo = hi;
  }

  // ---- in-wave merge of the 4 quarter lists (lanes q*16+pl, same pl) ----
  uint32_t arr[32];
#pragma unroll
  for (int k = 0; k < KSEL; ++k) arr[k] = m[k];
#pragma unroll
  for (int k = KSEL; k < 32; ++k) arr[k] = 0xFFFFFFFFu;

#pragma unroll
  for (int mask = 32; mask >= 16; mask >>= 1) {
    // Batcher half-cleaner against partner's reversed list -> bitonic 32-smallest
#pragma unroll
    for (int k = 0; k < 16; ++k) {
      const uint32_t sa = (uint32_t)__shfl_xor((int)arr[k],      mask);
      const uint32_t sb = (uint32_t)__shfl_xor((int)arr[31 - k], mask);
      arr[k]      = umin32(arr[k],      sb);
      arr[31 - k] = umin32(arr[31 - k], sa);
    }
    // bitonic -> sorted ascending (5 stages x 16 cmpswaps)
#pragma unroll
    for (int d = 16; d >= 1; d >>= 1)
#pragma unroll
      for (int k = 0; k < 32; ++k)
        if ((k & d) == 0) cmpswap(arr[k], arr[k | d]);
  }
  // arr[0..19] = final top-20 (identical in all 4 lanes of the point group)

  // ---- distributed exact recompute: lane q handles k = q,4+q,...,16+q ----
  int   id5[5];
  float d5[5];
  float dmn = 1e30f, dmx = -1e30f;
#pragma unroll
  for (int s = 0; s < 5; ++s) {
    const int k   = 4 * s + q;
    const int idk = (int)(arr[k] & 0xFFFu);
    id5[s] = idk;
    const float v0 = vd[idk * 3 + 0];
    const float v1 = vd[idk * 3 + 1];
    const float v2 = vd[idk * 3 + 2];
    const float sv = v0 * v0 + v1 * v1 + v2 * v2;
    const float dt = p0 * v0 + p1 * v1 + p2 * v2;
    const float dd = (sp + sv) - 2.0f * dt;   // raw, may be slightly negative
    d5[s] = dd;
    dmn = fminf(dmn, dd);
    dmx = fmaxf(dmx, dd);
  }
#pragma unroll
  for (int r = 16; r <= 32; r <<= 1) {
    dmx = fmaxf(dmx, __shfl_xor(dmx, r));
    dmn = fminf(dmn, __shfl_xor(dmn, r));
  }

  // ---- weights + blend partials ----
  const float invmax = 1.0f / dmx;
  float wsum = 0.0f, pb0 = 0.0f, pb1 = 0.0f, pb2 = 0.0f;
  float rb[9];
#pragma unroll
  for (int a = 0; a < 9; ++a) rb[a] = 0.0f;

#pragma unroll
  for (int s = 0; s < 5; ++s) {
    const int idk = id5[s];
    const float u = 1.0f - d5[s] * invmax;
    const float w = u * u;
    wsum += w;
    const float* Rp = Rm + idk * 9;
    const float r00 = Rp[0], r01 = Rp[1], r02 = Rp[2];
    const float r10 = Rp[3], r11 = Rp[4], r12 = Rp[5];
    const float r20 = Rp[6], r21 = Rp[7], r22 = Rp[8];
    const float g0 = gv[idk * 3 + 0];
    const float g1 = gv[idk * 3 + 1];
    const float g2 = gv[idk * 3 + 2];
    const float t0 = tv[idk * 3 + 0];
    const float t1 = tv[idk * 3 + 1];
    const float t2 = tv[idk * 3 + 2];
    const float x0 = p0 - g0 - t0;
    const float x1 = p1 - g1 - t1;
    const float x2 = p2 - g2 - t2;
    // p_i = sum_j R[j][i] * x_j + g_i   (einsum 'nkji,nkj->nki')
    pb0 += w * (r00 * x0 + r10 * x1 + r20 * x2 + g0);
    pb1 += w * (r01 * x0 + r11 * x1 + r21 * x2 + g1);
    pb2 += w * (r02 * x0 + r12 * x1 + r22 * x2 + g2);
    // R_blend[a][b] += w * R[b][a]  (R_inv = transpose)
    rb[0] += w * r00; rb[1] += w * r10; rb[2] += w * r20;
    rb[3] += w * r01; rb[4] += w * r11; rb[5] += w * r21;
    rb[6] += w * r02; rb[7] += w * r12; rb[8] += w * r22;
  }

  // ---- 13-value cross-lane sum over the 4 quarters ----
#pragma unroll
  for (int r = 16; r <= 32; r <<= 1) {
    wsum += __shfl_xor(wsum, r);
    pb0  += __shfl_xor(pb0, r);
    pb1  += __shfl_xor(pb1, r);
    pb2  += __shfl_xor(pb2, r);
#pragma unroll
    for (int a = 0; a < 9; ++a) rb[a] += __shfl_xor(rb[a], r);
  }

  if (q == 0) {
    const float inw = 1.0f / wsum;
    float o0 = pb0 * inw;
    if (dmn > 0.00021f) o0 = 1000000000.0f;   // far flag, post-blend
    float* po = out + (size_t)gi * 3;
    po[0] = o0; po[1] = pb1 * inw; po[2] = pb2 * inw;
    float* ro = out + (size_t)NPTS * 3 + (size_t)gi * 9;
#pragma unroll
    for (int a = 0; a < 9; ++a) ro[a] = rb[a] * inw;
  }
}

extern "C" void kernel_launch(void* const* d_in, const int* in_sizes, int n_in,
                              void* d_out, int out_size, void* d_ws, size_t ws_size,
                              hipStream_t stream) {
  const float* inp = (const float*)d_in[0];   // (65536, 35)
  const float* vd  = (const float*)d_in[1];   // (4096, 3)
  const float* Rm  = (const float*)d_in[2];   // (4096, 3, 3)
  const float* gv  = (const float*)d_in[3];   // (4096, 3)
  const float* tv  = (const float*)d_in[4];   // (4096, 3)
  float* out = (float*)d_out;                 // 65536*3 then 65536*9

  if (ws_size >= (size_t)NNODES * sizeof(float4)) {
    pack_nodes<<<NNODES / 256, 256, 0, stream>>>(vd, (float4*)d_ws);
    dg_kernel<true><<<NPTS / PPB, BT, 0, stream>>>(inp, vd, Rm, gv, tv,
                                                   (const float4*)d_ws, out);
  } else {
    dg_kernel<false><<<NPTS / PPB, BT, 0, stream>>>(inp, vd, Rm, gv, tv,
                                                    nullptr, out);
  }
}